// Round 3
// baseline (317.398 us; speedup 1.0000x reference)
//
#include <hip/hip_runtime.h>
#include <hip/hip_bf16.h>

#define DIMC 1536
#define NHC 16
#define HDC 96
#define BC 2
#define SC 2048
#define BSC (BC*SC)   // 4096 rows total

typedef __bf16 bf16x8 __attribute__((ext_vector_type(8)));
typedef __bf16 bf16x4 __attribute__((ext_vector_type(4)));
typedef float f32x4 __attribute__((ext_vector_type(4)));

// async global->LDS, 16B per lane: lane i -> lds_base + i*16 (lds base wave-uniform)
#define GLL(g, l)                                                              \
  __builtin_amdgcn_global_load_lds(                                            \
      (const __attribute__((address_space(1))) unsigned int*)(const void*)(g), \
      (__attribute__((address_space(3))) unsigned int*)(void*)(l), 16, 0, 0)

// (1/sqrt(96)) * log2(e): Q is pre-scaled by this so attention uses exp2 directly
#define QSCALE 0.14724448646421423f

// ---------------------------------------------------------------------------
// fp32 -> bf16 conversion for h + 4 weight matrices (region = blockIdx.y)
// ---------------------------------------------------------------------------
__global__ __launch_bounds__(256) void cvt_bf16_k(
    const float* __restrict__ s0, const float* __restrict__ s1,
    const float* __restrict__ s2, const float* __restrict__ s3,
    const float* __restrict__ s4,
    __bf16* __restrict__ d0, __bf16* __restrict__ d1, __bf16* __restrict__ d2,
    __bf16* __restrict__ d3, __bf16* __restrict__ d4) {
  const float* srcs[5] = {s0, s1, s2, s3, s4};
  __bf16* dsts[5] = {d0, d1, d2, d3, d4};
  const int ns[5] = {BSC * DIMC, DIMC * DIMC, DIMC * DIMC, DIMC * DIMC, DIMC * DIMC};
  int r = blockIdx.y;
  const float* src = srcs[r];
  __bf16* dst = dsts[r];
  int n = ns[r];
  int idx = (blockIdx.x * 256 + threadIdx.x) * 8;
  int stride = gridDim.x * 256 * 8;
  for (; idx < n; idx += stride) {
    float4 a = *(const float4*)(src + idx);
    float4 b = *(const float4*)(src + idx + 4);
    __bf16 o[8];
    o[0] = (__bf16)a.x; o[1] = (__bf16)a.y; o[2] = (__bf16)a.z; o[3] = (__bf16)a.w;
    o[4] = (__bf16)b.x; o[5] = (__bf16)b.y; o[6] = (__bf16)b.z; o[7] = (__bf16)b.w;
    *(uint4*)(dst + idx) = *(const uint4*)o;
  }
}

// ---------------------------------------------------------------------------
// RoPE sin/cos table: rt[(row*3+axis)*16 + f] = (cos, sin) of xyz[row*3+axis]*10000^(-f/16)
// ---------------------------------------------------------------------------
__global__ __launch_bounds__(256) void rope_tab_k(const int* __restrict__ xyz,
                                                  float2* __restrict__ rt) {
  int idx = blockIdx.x * 256 + threadIdx.x;  // < 4096*48
  int f = idx & 15;
  int ra = idx >> 4;  // row*3 + axis
  float invf = exp2f(-0.8304820237f * (float)f);
  float ang = (float)xyz[ra] * invf;
  float sn, cs;
  __sincosf(ang, &sn, &cs);
  rt[idx] = make_float2(cs, sn);
}

// ---------------------------------------------------------------------------
// GEMM core: C[4096,1536] = A * Bm^T, 128x128 tile, BK=64, GLL staging,
// XOR-swizzled LDS (row stride 64 elems = 128B; chunk' = chunk ^ (row&7)).
// ---------------------------------------------------------------------------
__device__ __forceinline__ void gemm_core(const __bf16* __restrict__ A,
                                          const __bf16* __restrict__ Bm,
                                          int bm, int bn, f32x4 acc[4][4],
                                          __bf16* As, __bf16* Bs) {
  const int t = threadIdx.x;
  const int wave = t >> 6, lane = t & 63;
  const int l15 = lane & 15, l4 = lane >> 4;
  const int wm = (wave >> 1) * 64, wn = (wave & 1) * 64;

  // staging: 4 chunks of 1024B per wave per matrix; lane i covers row (i/8), swizzled col
  const int srow8 = lane >> 3;                 // 0..7
  const int scol = ((lane & 7) ^ srow8) * 8;   // swizzled global col chunk
  const __bf16* gA = A + (size_t)(bm * 128 + wave * 32 + srow8) * DIMC + scol;
  const __bf16* gB = Bm + (size_t)(bn * 128 + wave * 32 + srow8) * DIMC + scol;
  __bf16* lA = As + wave * 2048;
  __bf16* lB = Bs + wave * 2048;

  for (int k0 = 0; k0 < DIMC; k0 += 64) {
    __syncthreads();  // previous iteration's fragment reads done
#pragma unroll
    for (int c = 0; c < 4; c++) {
      GLL(gA + c * 8 * DIMC, lA + c * 512);
      GLL(gB + c * 8 * DIMC, lB + c * 512);
    }
    gA += 64; gB += 64;
    __syncthreads();  // vmcnt(0) drain => tiles resident
#pragma unroll
    for (int k2 = 0; k2 < 2; k2++) {
      bf16x8 af[4], bfr[4];
#pragma unroll
      for (int i = 0; i < 4; i++) {
        int row = wm + i * 16 + l15;
        af[i] = *(const bf16x8*)&As[row * 64 + (((k2 * 4 + l4) ^ (l15 & 7)) * 8)];
      }
#pragma unroll
      for (int j = 0; j < 4; j++) {
        int row = wn + j * 16 + l15;
        bfr[j] = *(const bf16x8*)&Bs[row * 64 + (((k2 * 4 + l4) ^ (l15 & 7)) * 8)];
      }
#pragma unroll
      for (int i = 0; i < 4; i++)
#pragma unroll
        for (int j = 0; j < 4; j++)
          acc[i][j] = __builtin_amdgcn_mfma_f32_16x16x32_bf16(af[i], bfr[j], acc[i][j], 0, 0, 0);
    }
  }
}

// QKV GEMM: z=0 -> q (rope, pre-scaled), z=1 -> k (rope), z=2 -> v transposed to vT[bh][d][s]
__global__ __launch_bounds__(256, 2) void gemm_qkv_k(
    const __bf16* __restrict__ A, const __bf16* __restrict__ W0,
    const __bf16* __restrict__ W1, const __bf16* __restrict__ W2,
    const float2* __restrict__ rt,
    __bf16* __restrict__ qo, __bf16* __restrict__ ko, __bf16* __restrict__ vT) {
  __shared__ __bf16 As[128 * 64];
  __shared__ __bf16 Bs[128 * 64];
  const int z = blockIdx.z;
  const __bf16* W = (z == 0) ? W0 : (z == 1) ? W1 : W2;
  f32x4 acc[4][4] = {};
  gemm_core(A, W, blockIdx.x, blockIdx.y, acc, As, Bs);

  const int t = threadIdx.x;
  const int wave = t >> 6, lane = t & 63;
  const int l15 = lane & 15, l4 = lane >> 4;
  const int wm = (wave >> 1) * 64, wn = (wave & 1) * 64;

  if (z < 2) {
    // fused 3D RoPE via table; q additionally scaled by QSCALE
    __bf16* C = (z == 0) ? qo : ko;
    const float qs = (z == 0) ? QSCALE : 1.0f;
#pragma unroll
    for (int jp = 0; jp < 2; jp++) {
      int colbase = blockIdx.y * 128 + wn + jp * 32;
      int axis = (colbase % 96) >> 5;  // wave-uniform
#pragma unroll
      for (int i = 0; i < 4; i++) {
#pragma unroll
        for (int r = 0; r < 4; r++) {
          int row = blockIdx.x * 128 + wm + i * 16 + l4 * 4 + r;
          float2 t2 = rt[(row * 3 + axis) * 16 + l15];
          float e = acc[i][2 * jp][r], od = acc[i][2 * jp + 1][r];
          C[(size_t)row * DIMC + colbase + l15] = (__bf16)((e * t2.x - od * t2.y) * qs);
          C[(size_t)row * DIMC + colbase + l15 + 16] = (__bf16)((od * t2.x + e * t2.y) * qs);
        }
      }
    }
  } else {
    // V -> vT[bh][d][s], packed 4 bf16 (consecutive s) per store
#pragma unroll
    for (int i = 0; i < 4; i++)
#pragma unroll
      for (int j = 0; j < 4; j++) {
        int row0 = blockIdx.x * 128 + wm + i * 16 + l4 * 4;
        int col = blockIdx.y * 128 + wn + j * 16 + l15;
        int head = col / 96, d = col % 96;
        int b = row0 >> 11, s = row0 & 2047;
        bf16x4 pk;
#pragma unroll
        for (int r = 0; r < 4; r++) pk[r] = (__bf16)acc[i][j][r];
        *(bf16x4*)(vT + ((size_t)(b * 16 + head) * 96 + d) * 2048 + s) = pk;
      }
  }
}

__global__ __launch_bounds__(256, 2) void gemm_out_k(const __bf16* __restrict__ A,
                                                     const __bf16* __restrict__ W,
                                                     float* __restrict__ C) {
  __shared__ __bf16 As[128 * 64];
  __shared__ __bf16 Bs[128 * 64];
  f32x4 acc[4][4] = {};
  gemm_core(A, W, blockIdx.x, blockIdx.y, acc, As, Bs);
  const int t = threadIdx.x;
  const int wave = t >> 6, lane = t & 63;
  const int l15 = lane & 15, l4 = lane >> 4;
  const int wm = (wave >> 1) * 64, wn = (wave & 1) * 64;
#pragma unroll
  for (int i = 0; i < 4; i++)
#pragma unroll
    for (int j = 0; j < 4; j++) {
      int row = blockIdx.x * 128 + wm + i * 16 + l4 * 4;
      int col = blockIdx.y * 128 + wn + j * 16 + l15;
#pragma unroll
      for (int r = 0; r < 4; r++)
        C[(size_t)(row + r) * DIMC + col] = acc[i][j][r];
    }
}

// ---------------------------------------------------------------------------
// Flash attention, linear softmax with exp2 (Q pre-scaled by QSCALE).
// 256 threads = 4 waves; wave owns 64 q rows; block = 256 q rows.
// grid (S/256=8, B*NH=32) = 256 blocks = 1/CU. K-tile 64 keys.
// K/V staged by GLL into DOUBLE buffers: one barrier per iteration; GLLs for
// tile kt+1 issued before computing kt, drained by the end-of-iter barrier.
// V stored XOR-swizzled ([d][64] rows are 128B: chunk' = chunk ^ (d&7)).
// S^T = K.Q^T (swapped) so P writes are packed b64; P per-wave in LDS.
// ---------------------------------------------------------------------------
#define PS 72

__global__ __launch_bounds__(256, 1) void attn_k(const __bf16* __restrict__ q,
                                                 const __bf16* __restrict__ k,
                                                 const __bf16* __restrict__ vT,
                                                 __bf16* __restrict__ o) {
  const int qt = blockIdx.x;
  const int bh = blockIdx.y;
  const int b = bh >> 4, h = bh & 15;
  const int t = threadIdx.x;
  const int wave = t >> 6, lane = t & 63;
  const int l15 = lane & 15, l4 = lane >> 4;

  __shared__ __bf16 Ks[2][64 * 96];   // 24576 B
  __shared__ __bf16 Vs[2][96 * 64];   // 24576 B (swizzled)
  __shared__ __bf16 Ps[4][64 * PS];   // 36864 B
  __shared__ float Ls[256];

  // Q fragments (fixed for whole kernel): wave rows qt*256 + wave*64 + mt*16 + l15
  bf16x8 qf[4][3];
  {
    const __bf16* gq =
        q + (size_t)(b * SC + qt * 256 + wave * 64 + l15) * DIMC + h * HDC + l4 * 8;
#pragma unroll
    for (int mt = 0; mt < 4; mt++)
#pragma unroll
      for (int ks = 0; ks < 3; ks++)
        qf[mt][ks] = *(const bf16x8*)(gq + (size_t)mt * 16 * DIMC + ks * 32);
  }

  // GLL source addresses (3 chunks per wave for K, 3 for V)
  const __bf16* gK[3];
  const __bf16* gV[3];
#pragma unroll
  for (int j = 0; j < 3; j++) {
    int oe = (wave * 3 + j) * 512 + lane * 8;
    int kr = oe / 96, kc = oe % 96;                 // K row-major [64][96]
    gK[j] = k + (size_t)(b * SC + kr) * DIMC + h * HDC + kc;
    int vr = (wave * 3 + j) * 8 + (lane >> 3);      // V [d][64], swizzled cols
    int vc = ((lane & 7) ^ (lane >> 3)) * 8;
    gV[j] = vT + ((size_t)bh * HDC + vr) * SC + vc;
  }

  // prologue: stage tile 0 into buffer 0
#pragma unroll
  for (int j = 0; j < 3; j++) {
    GLL(gK[j], &Ks[0][(wave * 3 + j) * 512]);
    GLL(gV[j], &Vs[0][(wave * 3 + j) * 512]);
  }
  __syncthreads();

  f32x4 oacc[4][6] = {};
  float lacc[4] = {0.f, 0.f, 0.f, 0.f};
  __bf16* Pw = &Ps[wave][0];

  for (int kt = 0; kt < SC / 64; kt++) {
    const int cur = kt & 1, nxt = cur ^ 1;
    if (kt + 1 < SC / 64) {  // async prefetch of next tile; no wait until barrier
#pragma unroll
      for (int j = 0; j < 3; j++) {
        gK[j] += (size_t)64 * DIMC;
        gV[j] += 64;
        GLL(gK[j], &Ks[nxt][(wave * 3 + j) * 512]);
        GLL(gV[j], &Vs[nxt][(wave * 3 + j) * 512]);
      }
    }
    const __bf16* Kc = &Ks[cur][0];
    const __bf16* Vc = &Vs[cur][0];

    // S^T = K.Q^T per 16-key tile, exp2 + packed P write serialized per tile
#pragma unroll
    for (int kk = 0; kk < 4; kk++) {
      bf16x8 kf[3];
#pragma unroll
      for (int ks = 0; ks < 3; ks++)
        kf[ks] = *(const bf16x8*)&Kc[(kk * 16 + l15) * 96 + ks * 32 + l4 * 8];
      f32x4 sacc[4] = {};
#pragma unroll
      for (int ks = 0; ks < 3; ks++)
#pragma unroll
        for (int mt = 0; mt < 4; mt++)
          sacc[mt] = __builtin_amdgcn_mfma_f32_16x16x32_bf16(kf[ks], qf[mt][ks], sacc[mt], 0, 0, 0);
#pragma unroll
      for (int mt = 0; mt < 4; mt++) {
        float p0 = exp2f(sacc[mt][0]);
        float p1 = exp2f(sacc[mt][1]);
        float p2 = exp2f(sacc[mt][2]);
        float p3 = exp2f(sacc[mt][3]);
        lacc[mt] += (p0 + p1) + (p2 + p3);
        bf16x4 pb;
        pb[0] = (__bf16)p0; pb[1] = (__bf16)p1; pb[2] = (__bf16)p2; pb[3] = (__bf16)p3;
        *(bf16x4*)&Pw[(mt * 16 + l15) * PS + kk * 16 + l4 * 4] = pb;
      }
    }

    // O += P(64x64) . V(64x96)
#pragma unroll
    for (int k2 = 0; k2 < 2; k2++) {
      bf16x8 pf[4];
#pragma unroll
      for (int mt = 0; mt < 4; mt++)
        pf[mt] = *(const bf16x8*)&Pw[(mt * 16 + l15) * PS + k2 * 32 + l4 * 8];
#pragma unroll
      for (int nt = 0; nt < 6; nt++) {
        bf16x8 vf = *(const bf16x8*)&Vc[(nt * 16 + l15) * 64 +
                                        (((k2 * 4 + l4) ^ (l15 & 7)) * 8)];
#pragma unroll
        for (int mt = 0; mt < 4; mt++)
          oacc[mt][nt] = __builtin_amdgcn_mfma_f32_16x16x32_bf16(pf[mt], vf, oacc[mt][nt], 0, 0, 0);
      }
    }
    __syncthreads();  // waits vmcnt(0): prefetched GLLs resident; all LDS reads of cur done
  }

  // denominators (reduce over l4 groups), then normalize + store
#pragma unroll
  for (int mt = 0; mt < 4; mt++) {
    float s = lacc[mt];
    s += __shfl_xor(s, 16);
    s += __shfl_xor(s, 32);
    if (l4 == 0) Ls[wave * 64 + mt * 16 + l15] = s;
  }
#pragma unroll
  for (int mt = 0; mt < 4; mt++)
#pragma unroll
    for (int r = 0; r < 4; r++) {
      int lrow = wave * 64 + mt * 16 + l4 * 4 + r;
      float inv = 1.0f / Ls[lrow];
      int row = qt * 256 + lrow;
      __bf16* po = o + (size_t)(b * SC + row) * DIMC + h * HDC;
#pragma unroll
      for (int nt = 0; nt < 6; nt++)
        po[nt * 16 + l15] = (__bf16)(oacc[mt][nt][r] * inv);
    }
}

// ---------------------------------------------------------------------------
extern "C" void kernel_launch(void* const* d_in, const int* in_sizes, int n_in,
                              void* d_out, int out_size, void* d_ws, size_t ws_size,
                              hipStream_t stream) {
  const int* xyz = (const int*)d_in[0];
  const float* h = (const float*)d_in[1];
  const float* wq = (const float*)d_in[2];
  const float* wk = (const float*)d_in[3];
  const float* wv = (const float*)d_in[4];
  const float* wo = (const float*)d_in[5];
  float* out = (float*)d_out;

  __bf16* p = (__bf16*)d_ws;
  __bf16* hb = p;  p += (size_t)BSC * DIMC;
  __bf16* wqb = p; p += (size_t)DIMC * DIMC;
  __bf16* wkb = p; p += (size_t)DIMC * DIMC;
  __bf16* wvb = p; p += (size_t)DIMC * DIMC;
  __bf16* wob = p; p += (size_t)DIMC * DIMC;
  __bf16* qb = p;  p += (size_t)BSC * DIMC;
  __bf16* kb = p;  p += (size_t)BSC * DIMC;
  __bf16* vTb = p; p += (size_t)BSC * DIMC;
  __bf16* ab = p;  p += (size_t)BSC * DIMC;
  float2* rt = (float2*)p;  // 4096*48 float2 = 1.5 MB

  rope_tab_k<<<dim3(768), 256, 0, stream>>>(xyz, rt);
  cvt_bf16_k<<<dim3(3072, 5), 256, 0, stream>>>(h, wq, wk, wv, wo, hb, wqb, wkb, wvb, wob);
  gemm_qkv_k<<<dim3(32, 12, 3), 256, 0, stream>>>(hb, wqb, wkb, wvb, rt, qb, kb, vTb);
  attn_k<<<dim3(SC / 256, BC * NHC), 256, 0, stream>>>(qb, kb, vTb, ab);
  gemm_out_k<<<dim3(32, 12), 256, 0, stream>>>(ab, wob, out);
}

// Round 4
// 255.031 us; speedup vs baseline: 1.2445x; 1.2445x over previous
//
#include <hip/hip_runtime.h>
#include <hip/hip_bf16.h>

#define DIMC 1536
#define NHC 16
#define HDC 96
#define BC 2
#define SC 2048
#define BSC (BC*SC)   // 4096 rows total

typedef __bf16 bf16x8 __attribute__((ext_vector_type(8)));
typedef __bf16 bf16x4 __attribute__((ext_vector_type(4)));
typedef float f32x4 __attribute__((ext_vector_type(4)));

// async global->LDS, 16B per lane: lane i -> lds_base + i*16 (lds base wave-uniform)
#define GLL(g, l)                                                              \
  __builtin_amdgcn_global_load_lds(                                            \
      (const __attribute__((address_space(1))) unsigned int*)(const void*)(g), \
      (__attribute__((address_space(3))) unsigned int*)(void*)(l), 16, 0, 0)

// (1/sqrt(96)) * log2(e): Q is pre-scaled by this so attention uses exp2 directly
#define QSCALE 0.14724448646421423f

// ---------------------------------------------------------------------------
// fp32 -> bf16 conversion (y=0..4) + RoPE table build (y=5).
// rt[(row*3+axis)*16 + f] = (cos, sin) of xyz[row*3+axis]*10000^(-f/16)
// ---------------------------------------------------------------------------
__global__ __launch_bounds__(256) void cvt_bf16_k(
    const float* __restrict__ s0, const float* __restrict__ s1,
    const float* __restrict__ s2, const float* __restrict__ s3,
    const float* __restrict__ s4,
    __bf16* __restrict__ d0, __bf16* __restrict__ d1, __bf16* __restrict__ d2,
    __bf16* __restrict__ d3, __bf16* __restrict__ d4,
    const int* __restrict__ xyz, float2* __restrict__ rt) {
  int r = blockIdx.y;
  if (r == 5) {
    int idx = blockIdx.x * 256 + threadIdx.x;
    if (idx < BSC * 48) {
      int f = idx & 15;
      int ra = idx >> 4;  // row*3 + axis
      float invf = exp2f(-0.8304820237f * (float)f);
      float ang = (float)xyz[ra] * invf;
      float sn, cs;
      __sincosf(ang, &sn, &cs);
      rt[idx] = make_float2(cs, sn);
    }
    return;
  }
  const float* srcs[5] = {s0, s1, s2, s3, s4};
  __bf16* dsts[5] = {d0, d1, d2, d3, d4};
  const int ns[5] = {BSC * DIMC, DIMC * DIMC, DIMC * DIMC, DIMC * DIMC, DIMC * DIMC};
  const float* src = srcs[r];
  __bf16* dst = dsts[r];
  int n = ns[r];
  int idx = (blockIdx.x * 256 + threadIdx.x) * 8;
  int stride = gridDim.x * 256 * 8;
  for (; idx < n; idx += stride) {
    float4 a = *(const float4*)(src + idx);
    float4 b = *(const float4*)(src + idx + 4);
    __bf16 o[8];
    o[0] = (__bf16)a.x; o[1] = (__bf16)a.y; o[2] = (__bf16)a.z; o[3] = (__bf16)a.w;
    o[4] = (__bf16)b.x; o[5] = (__bf16)b.y; o[6] = (__bf16)b.z; o[7] = (__bf16)b.w;
    *(uint4*)(dst + idx) = *(const uint4*)o;
  }
}

// ---------------------------------------------------------------------------
// GEMM core: C[4096,1536] = A * Bm^T, 128x128 tile, BK=64, GLL staging,
// XOR-swizzled LDS (row stride 64 elems = 128B; chunk' = chunk ^ (row&7)).
// ---------------------------------------------------------------------------
__device__ __forceinline__ void gemm_core(const __bf16* __restrict__ A,
                                          const __bf16* __restrict__ Bm,
                                          int bm, int bn, f32x4 acc[4][4],
                                          __bf16* As, __bf16* Bs) {
  const int t = threadIdx.x;
  const int wave = t >> 6, lane = t & 63;
  const int l15 = lane & 15, l4 = lane >> 4;
  const int wm = (wave >> 1) * 64, wn = (wave & 1) * 64;

  const int srow8 = lane >> 3;                 // 0..7
  const int scol = ((lane & 7) ^ srow8) * 8;   // swizzled global col chunk
  const __bf16* gA = A + (size_t)(bm * 128 + wave * 32 + srow8) * DIMC + scol;
  const __bf16* gB = Bm + (size_t)(bn * 128 + wave * 32 + srow8) * DIMC + scol;
  __bf16* lA = As + wave * 2048;
  __bf16* lB = Bs + wave * 2048;

  for (int k0 = 0; k0 < DIMC; k0 += 64) {
    __syncthreads();
#pragma unroll
    for (int c = 0; c < 4; c++) {
      GLL(gA + c * 8 * DIMC, lA + c * 512);
      GLL(gB + c * 8 * DIMC, lB + c * 512);
    }
    gA += 64; gB += 64;
    __syncthreads();
#pragma unroll
    for (int k2 = 0; k2 < 2; k2++) {
      bf16x8 af[4], bfr[4];
#pragma unroll
      for (int i = 0; i < 4; i++) {
        int row = wm + i * 16 + l15;
        af[i] = *(const bf16x8*)&As[row * 64 + (((k2 * 4 + l4) ^ (l15 & 7)) * 8)];
      }
#pragma unroll
      for (int j = 0; j < 4; j++) {
        int row = wn + j * 16 + l15;
        bfr[j] = *(const bf16x8*)&Bs[row * 64 + (((k2 * 4 + l4) ^ (l15 & 7)) * 8)];
      }
#pragma unroll
      for (int i = 0; i < 4; i++)
#pragma unroll
        for (int j = 0; j < 4; j++)
          acc[i][j] = __builtin_amdgcn_mfma_f32_16x16x32_bf16(af[i], bfr[j], acc[i][j], 0, 0, 0);
    }
  }
}

// QKV GEMM: z=0 -> q (rope, pre-scaled), z=1 -> k (rope), z=2 -> v transposed to vT[bh][d][s]
__global__ __launch_bounds__(256, 2) void gemm_qkv_k(
    const __bf16* __restrict__ A, const __bf16* __restrict__ W0,
    const __bf16* __restrict__ W1, const __bf16* __restrict__ W2,
    const float2* __restrict__ rt,
    __bf16* __restrict__ qo, __bf16* __restrict__ ko, __bf16* __restrict__ vT) {
  __shared__ __bf16 As[128 * 64];
  __shared__ __bf16 Bs[128 * 64];
  const int z = blockIdx.z;
  const __bf16* W = (z == 0) ? W0 : (z == 1) ? W1 : W2;
  f32x4 acc[4][4] = {};
  gemm_core(A, W, blockIdx.x, blockIdx.y, acc, As, Bs);

  const int t = threadIdx.x;
  const int wave = t >> 6, lane = t & 63;
  const int l15 = lane & 15, l4 = lane >> 4;
  const int wm = (wave >> 1) * 64, wn = (wave & 1) * 64;

  if (z < 2) {
    __bf16* C = (z == 0) ? qo : ko;
    const float qs = (z == 0) ? QSCALE : 1.0f;
#pragma unroll
    for (int jp = 0; jp < 2; jp++) {
      int colbase = blockIdx.y * 128 + wn + jp * 32;
      int axis = (colbase % 96) >> 5;  // wave-uniform
#pragma unroll
      for (int i = 0; i < 4; i++) {
#pragma unroll
        for (int r = 0; r < 4; r++) {
          int row = blockIdx.x * 128 + wm + i * 16 + l4 * 4 + r;
          float2 t2 = rt[(row * 3 + axis) * 16 + l15];
          float e = acc[i][2 * jp][r], od = acc[i][2 * jp + 1][r];
          C[(size_t)row * DIMC + colbase + l15] = (__bf16)((e * t2.x - od * t2.y) * qs);
          C[(size_t)row * DIMC + colbase + l15 + 16] = (__bf16)((od * t2.x + e * t2.y) * qs);
        }
      }
    }
  } else {
#pragma unroll
    for (int i = 0; i < 4; i++)
#pragma unroll
      for (int j = 0; j < 4; j++) {
        int row0 = blockIdx.x * 128 + wm + i * 16 + l4 * 4;
        int col = blockIdx.y * 128 + wn + j * 16 + l15;
        int head = col / 96, d = col % 96;
        int b = row0 >> 11, s = row0 & 2047;
        bf16x4 pk;
#pragma unroll
        for (int r = 0; r < 4; r++) pk[r] = (__bf16)acc[i][j][r];
        *(bf16x4*)(vT + ((size_t)(b * 16 + head) * 96 + d) * 2048 + s) = pk;
      }
  }
}

__global__ __launch_bounds__(256, 2) void gemm_out_k(const __bf16* __restrict__ A,
                                                     const __bf16* __restrict__ W,
                                                     float* __restrict__ C) {
  __shared__ __bf16 As[128 * 64];
  __shared__ __bf16 Bs[128 * 64];
  f32x4 acc[4][4] = {};
  gemm_core(A, W, blockIdx.x, blockIdx.y, acc, As, Bs);
  const int t = threadIdx.x;
  const int wave = t >> 6, lane = t & 63;
  const int l15 = lane & 15, l4 = lane >> 4;
  const int wm = (wave >> 1) * 64, wn = (wave & 1) * 64;
#pragma unroll
  for (int i = 0; i < 4; i++)
#pragma unroll
    for (int j = 0; j < 4; j++) {
      int row = blockIdx.x * 128 + wm + i * 16 + l4 * 4;
      int col = blockIdx.y * 128 + wn + j * 16 + l15;
#pragma unroll
      for (int r = 0; r < 4; r++)
        C[(size_t)(row + r) * DIMC + col] = acc[i][j][r];
    }
}

// ---------------------------------------------------------------------------
// Flash attention, linear softmax (exp2, Q pre-scaled). In-block key split:
// 512 threads = 8 waves = 2 key-groups x 4 waves. Group g covers keys
// [g*1024,(g+1)*1024) in 32-key tiles (32 iters), over the SAME 256 q rows
// (wave owns 64 q rows). GLL double-buffered K/V, 1 barrier/iter. Partial
// O (fp32) + denominators merged through LDS at the end (linear => pure add).
// Within each group: waves 0-1 stage K, waves 2-3 stage V.
// ---------------------------------------------------------------------------
__global__ __launch_bounds__(512, 2) void attn_k(const __bf16* __restrict__ q,
                                                 const __bf16* __restrict__ k,
                                                 const __bf16* __restrict__ vT,
                                                 __bf16* __restrict__ o) {
  const int qt = blockIdx.x;    // 0..7 (256 q rows each)
  const int bh = blockIdx.y;
  const int b = bh >> 4, h = bh & 15;
  const int t = threadIdx.x;
  const int wave = t >> 6, lane = t & 63;
  const int l15 = lane & 15, l4 = lane >> 4;
  const int grp = wave >> 2, wgrp = wave & 3;

  // smem: Ks[2][2][32*96] | Vs[2][2][96*32] | Ps[8][64*72] | Ls[2][256]
  // final phase reuses Ks/Vs/Ps region as FB = float[4][64*96]
  __shared__ __attribute__((aligned(16))) char smem[124928];
  __bf16* Ks = (__bf16*)smem;
  __bf16* Vs = (__bf16*)(smem + 24576);
  __bf16* Ps = (__bf16*)(smem + 49152);
  float* Ls = (float*)(smem + 122880);
  float* FB = (float*)smem;

  // Q fragments (persist all iters); q rows = qt*256 + wgrp*64 + mt*16 + l15
  bf16x8 qf[4][3];
  {
    const __bf16* gq =
        q + (size_t)(b * SC + qt * 256 + wgrp * 64 + l15) * DIMC + h * HDC + l4 * 8;
#pragma unroll
    for (int mt = 0; mt < 4; mt++)
#pragma unroll
      for (int ks = 0; ks < 3; ks++)
        qf[mt][ks] = *(const bf16x8*)(gq + (size_t)mt * 16 * DIMC + ks * 32);
  }

  // staging role: waves 0-1 of group stage K tile (32x96), waves 2-3 stage V tile (96x32)
  const bool isK = (wgrp < 2);
  const int cw = isK ? wgrp : (wgrp - 2);  // 0/1
  const __bf16* gbase = isK ? k : vT;
  const int inc = isK ? 32 * DIMC : 32;
  int goffs[3];
  int ldoffs[3];
#pragma unroll
  for (int r = 0; r < 3; r++) {
    int off = (cw * 3 + r) * 512 + lane * 8;  // elem offset within 6KB half-tile
    ldoffs[r] = (cw * 3 + r) * 512;
    if (isK) {
      int key = off / 96, d = off % 96;
      goffs[r] = (b * SC + grp * 1024 + key) * DIMC + h * HDC + d;
    } else {
      int d = off >> 5, key = off & 31;
      goffs[r] = (bh * HDC + d) * SC + grp * 1024 + key;
    }
  }

  // prologue: stage tile 0 into buffer 0
#pragma unroll
  for (int r = 0; r < 3; r++) {
    __bf16* dst = (isK ? (Ks + grp * 3072) : (Vs + grp * 3072)) + ldoffs[r];
    GLL(gbase + goffs[r], dst);
  }
  __syncthreads();

  f32x4 oacc[4][6] = {};
  float lacc[4] = {0.f, 0.f, 0.f, 0.f};
  __bf16* Pw = &Ps[wave * 4608];

  for (int kt = 0; kt < 32; kt++) {
    const int cur = kt & 1, nxt = cur ^ 1;
    if (kt + 1 < 32) {  // async prefetch next 32-key tile
#pragma unroll
      for (int r = 0; r < 3; r++) {
        goffs[r] += inc;
        __bf16* dst =
            (isK ? (Ks + (nxt * 2 + grp) * 3072) : (Vs + (nxt * 2 + grp) * 3072)) + ldoffs[r];
        GLL(gbase + goffs[r], dst);
      }
    }
    const __bf16* Kc = Ks + (cur * 2 + grp) * 3072;  // [32][96]
    const __bf16* Vc = Vs + (cur * 2 + grp) * 3072;  // [96][32]

    // S^T = K.Q^T per 16-key subtile; exp2 + packed P write
#pragma unroll
    for (int kk = 0; kk < 2; kk++) {
      bf16x8 kf[3];
#pragma unroll
      for (int ks = 0; ks < 3; ks++)
        kf[ks] = *(const bf16x8*)&Kc[(kk * 16 + l15) * 96 + ks * 32 + l4 * 8];
      f32x4 sacc[4] = {};
#pragma unroll
      for (int ks = 0; ks < 3; ks++)
#pragma unroll
        for (int mt = 0; mt < 4; mt++)
          sacc[mt] = __builtin_amdgcn_mfma_f32_16x16x32_bf16(kf[ks], qf[mt][ks], sacc[mt], 0, 0, 0);
#pragma unroll
      for (int mt = 0; mt < 4; mt++) {
        float p0 = __builtin_amdgcn_exp2f(sacc[mt][0]);
        float p1 = __builtin_amdgcn_exp2f(sacc[mt][1]);
        float p2 = __builtin_amdgcn_exp2f(sacc[mt][2]);
        float p3 = __builtin_amdgcn_exp2f(sacc[mt][3]);
        lacc[mt] += (p0 + p1) + (p2 + p3);
        bf16x4 pb;
        pb[0] = (__bf16)p0; pb[1] = (__bf16)p1; pb[2] = (__bf16)p2; pb[3] = (__bf16)p3;
        *(bf16x4*)&Pw[(mt * 16 + l15) * 72 + kk * 16 + l4 * 4] = pb;
      }
    }

    // O += P(64x32) . V(32x96)
    {
      bf16x8 pf[4];
#pragma unroll
      for (int mt = 0; mt < 4; mt++)
        pf[mt] = *(const bf16x8*)&Pw[(mt * 16 + l15) * 72 + l4 * 8];
#pragma unroll
      for (int nt = 0; nt < 6; nt++) {
        bf16x8 vf = *(const bf16x8*)&Vc[(nt * 16 + l15) * 32 + l4 * 8];
#pragma unroll
        for (int mt = 0; mt < 4; mt++)
          oacc[mt][nt] = __builtin_amdgcn_mfma_f32_16x16x32_bf16(pf[mt], vf, oacc[mt][nt], 0, 0, 0);
      }
    }
    __syncthreads();  // drains prefetch GLLs; all waves done reading cur
  }

  // per-group denominators -> Ls[grp][256]
#pragma unroll
  for (int mt = 0; mt < 4; mt++) {
    float s = lacc[mt];
    s += __shfl_xor(s, 16);
    s += __shfl_xor(s, 32);
    if (l4 == 0) Ls[grp * 256 + wgrp * 64 + mt * 16 + l15] = s;
  }
  // group 1 parks partial O in LDS (fp32)
  if (grp == 1) {
#pragma unroll
    for (int mt = 0; mt < 4; mt++)
#pragma unroll
      for (int nt = 0; nt < 6; nt++)
#pragma unroll
        for (int r = 0; r < 4; r++)
          FB[wgrp * 6144 + (mt * 16 + l4 * 4 + r) * 96 + nt * 16 + l15] = oacc[mt][nt][r];
  }
  __syncthreads();
  // group 0 merges + normalizes + stores
  if (grp == 0) {
#pragma unroll
    for (int mt = 0; mt < 4; mt++)
#pragma unroll
      for (int r = 0; r < 4; r++) {
        int rowl = wgrp * 64 + mt * 16 + l4 * 4 + r;
        float inv = 1.0f / (Ls[rowl] + Ls[256 + rowl]);
        int row = qt * 256 + rowl;
        __bf16* po = o + (size_t)(b * SC + row) * DIMC + h * HDC;
#pragma unroll
        for (int nt = 0; nt < 6; nt++) {
          float v = oacc[mt][nt][r] +
                    FB[wgrp * 6144 + (mt * 16 + l4 * 4 + r) * 96 + nt * 16 + l15];
          po[nt * 16 + l15] = (__bf16)(v * inv);
        }
      }
  }
}

// ---------------------------------------------------------------------------
extern "C" void kernel_launch(void* const* d_in, const int* in_sizes, int n_in,
                              void* d_out, int out_size, void* d_ws, size_t ws_size,
                              hipStream_t stream) {
  const int* xyz = (const int*)d_in[0];
  const float* h = (const float*)d_in[1];
  const float* wq = (const float*)d_in[2];
  const float* wk = (const float*)d_in[3];
  const float* wv = (const float*)d_in[4];
  const float* wo = (const float*)d_in[5];
  float* out = (float*)d_out;

  __bf16* p = (__bf16*)d_ws;
  __bf16* hb = p;  p += (size_t)BSC * DIMC;
  __bf16* wqb = p; p += (size_t)DIMC * DIMC;
  __bf16* wkb = p; p += (size_t)DIMC * DIMC;
  __bf16* wvb = p; p += (size_t)DIMC * DIMC;
  __bf16* wob = p; p += (size_t)DIMC * DIMC;
  __bf16* qb = p;  p += (size_t)BSC * DIMC;
  __bf16* kb = p;  p += (size_t)BSC * DIMC;
  __bf16* vTb = p; p += (size_t)BSC * DIMC;
  __bf16* ab = p;  p += (size_t)BSC * DIMC;
  float2* rt = (float2*)p;  // 4096*48 float2 = 1.5 MB

  cvt_bf16_k<<<dim3(3072, 6), 256, 0, stream>>>(h, wq, wk, wv, wo, hb, wqb, wkb, wvb, wob,
                                                xyz, rt);
  gemm_qkv_k<<<dim3(32, 12, 3), 256, 0, stream>>>(hb, wqb, wkb, wvb, rt, qb, kb, vTb);
  attn_k<<<dim3(SC / 256, BC * NHC), 512, 0, stream>>>(qb, kb, vTb, ab);
  gemm_out_k<<<dim3(32, 12), 256, 0, stream>>>(ab, wob, out);
}